// Round 2
// baseline (987.904 us; speedup 1.0000x reference)
//
#include <hip/hip_runtime.h>
#include <math.h>

#define SEQ 2048
#define DM 512
#define NHH 8
#define NB 4
#define MR (NB*SEQ)     // 8192
#define NBH (NB*NHH)    // 32

typedef __attribute__((ext_vector_type(8))) short bf16x8;
typedef __attribute__((ext_vector_type(4))) float f32x4;
#define MFMA __builtin_amdgcn_mfma_f32_16x16x32_bf16

// ---- ws byte offsets (total ~53 MB) ----
#define OFF_XB   0ull            // x bf16 (8MB); reused as Vt bf16 after QKV GEMMs
#define OFF_QB   8388608ull      // Q bf16 (8MB)
#define OFF_KB   16777216ull     // K bf16 (8MB); reused as gated bf16 after attention
#define OFF_VB   25165824ull     // V bf16 (8MB); reused as attended bf16 (V dead after vtrans)
#define OFF_ATTF 33554432ull     // attended f32 (16MB)
#define OFF_WQT  50331648ull
#define OFF_WKT  50855936ull
#define OFF_WVT  51380224ull
#define OFF_WGT  51904512ull
#define OFF_WOT  52428800ull
#define OFF_TS   52953088ull     // 3 floats
#define OUT_ATTN 4194304ull      // float offset of attn within d_out

__device__ __forceinline__ unsigned short f2b(float f) {
  union { float f; unsigned u; } v; v.f = f;
  unsigned r = v.u + 0x7FFFu + ((v.u >> 16) & 1u);
  return (unsigned short)(r >> 16);
}
__device__ __forceinline__ float b2f(unsigned v16) {
  union { unsigned u; float f; } v; v.u = v16 << 16; return v.f;
}
__device__ __forceinline__ float sigm(float x) { return 1.0f / (1.0f + __expf(-x)); }

// ---------------------------------------------------------------------------
// trust scalars: a = Wt.Wt, b = Wt.bt, c = bt.bt  (exact algebraic reduction of
// the trust_projection outer product: tp_q.tp_k = a*tq*tk + b*(tq+tk) + c)
// ---------------------------------------------------------------------------
__global__ void k_trust_scalars(const float* __restrict__ Wt,
                                const float* __restrict__ bt,
                                float* __restrict__ ts) {
  int l = threadIdx.x;  // 64
  float w = Wt[l], b = bt[l];
  float a = w * w, bb = w * b, c = b * b;
  #pragma unroll
  for (int off = 32; off; off >>= 1) {
    a  += __shfl_down(a, off);
    bb += __shfl_down(bb, off);
    c  += __shfl_down(c, off);
  }
  if (l == 0) { ts[0] = a; ts[1] = bb; ts[2] = c; }
}

// ---------------------------------------------------------------------------
// x fp32 -> bf16
// ---------------------------------------------------------------------------
__global__ __launch_bounds__(256) void k_cvt_x(const float* __restrict__ x,
                                               unsigned short* __restrict__ xb) {
  const int i = (blockIdx.x * 256 + threadIdx.x) * 8;
  float4 a = *(const float4*)(x + i);
  float4 b = *(const float4*)(x + i + 4);
  uint4 o;
  o.x = (unsigned)f2b(a.x) | ((unsigned)f2b(a.y) << 16);
  o.y = (unsigned)f2b(a.z) | ((unsigned)f2b(a.w) << 16);
  o.z = (unsigned)f2b(b.x) | ((unsigned)f2b(b.y) << 16);
  o.w = (unsigned)f2b(b.z) | ((unsigned)f2b(b.w) << 16);
  *(uint4*)(xb + i) = o;
}

// ---------------------------------------------------------------------------
// W [512][512] fp32 -> Wt [n][k] bf16 (transpose + convert)
// ---------------------------------------------------------------------------
__global__ __launch_bounds__(256) void k_wtrans(const float* __restrict__ W,
                                                unsigned short* __restrict__ Wt) {
  __shared__ unsigned short tile[64][74];
  const int k0 = blockIdx.x * 64, n0 = blockIdx.y * 64, t = threadIdx.x;
  const int rr = t >> 4, c4 = (t & 15) * 4;
  #pragma unroll
  for (int rep = 0; rep < 4; rep++) {
    const int r = rr + rep * 16;
    float4 v = *(const float4*)(W + (size_t)(k0 + r) * 512 + n0 + c4);
    tile[c4][r] = f2b(v.x); tile[c4 + 1][r] = f2b(v.y);
    tile[c4 + 2][r] = f2b(v.z); tile[c4 + 3][r] = f2b(v.w);
  }
  __syncthreads();
  #pragma unroll
  for (int rep = 0; rep < 4; rep++) {
    const int n = rr + rep * 16;
    const unsigned short* p = &tile[n][c4];
    uint2 o;
    o.x = (unsigned)p[0] | ((unsigned)p[1] << 16);
    o.y = (unsigned)p[2] | ((unsigned)p[3] << 16);
    *(uint2*)(Wt + (size_t)(n0 + n) * 512 + k0 + c4) = o;
  }
}

// ---------------------------------------------------------------------------
// V bf16 [8192][512] -> Vt bf16 [bh*64 + d][2048]
// ---------------------------------------------------------------------------
__global__ __launch_bounds__(256) void k_vtrans(const unsigned short* __restrict__ Vb,
                                                unsigned short* __restrict__ Vt) {
  __shared__ unsigned short tile[64][74];
  const int s0 = blockIdx.x * 64;
  const int bh = blockIdx.y, b = bh >> 3, h = bh & 7;
  const int t = threadIdx.x, rr = t >> 4, c4 = (t & 15) * 4;
  #pragma unroll
  for (int rep = 0; rep < 4; rep++) {
    const int r = rr + rep * 16;
    uint2 v = *(const uint2*)(Vb + (size_t)(b * SEQ + s0 + r) * 512 + h * 64 + c4);
    tile[c4][r] = v.x & 0xffff; tile[c4 + 1][r] = v.x >> 16;
    tile[c4 + 2][r] = v.y & 0xffff; tile[c4 + 3][r] = v.y >> 16;
  }
  __syncthreads();
  #pragma unroll
  for (int rep = 0; rep < 4; rep++) {
    const int d = rr + rep * 16;
    const unsigned short* p = &tile[d][c4];
    uint2 o;
    o.x = (unsigned)p[0] | ((unsigned)p[1] << 16);
    o.y = (unsigned)p[2] | ((unsigned)p[3] << 16);
    *(uint2*)(Vt + (size_t)(bh * 64 + d) * SEQ + s0 + c4) = o;
  }
}

// ---------------------------------------------------------------------------
// MFMA GEMM: C[m][n] = sum_k A[m][k]*Bt[n][k]  (A bf16 [M][512], Bt bf16 [512][512])
// BM=64 BN=128 BK=64, 256 thr, waves 2x2 (each 32x64). grid (128,4).
// mode 0: obf = bf16(C + bias)                      (QKV)
// mode 1: obf = bf16(Afp * sigm(C + bias + trust[m]*wg512[n]))   (gate)
// mode 2: ofp = C + bias                            (output proj)
// ---------------------------------------------------------------------------
__global__ __launch_bounds__(256) void k_gemm(
    const unsigned short* __restrict__ A, const unsigned short* __restrict__ Bt,
    const float* __restrict__ bias, const float* __restrict__ wg512,
    const float* __restrict__ trust, const float* __restrict__ Afp,
    unsigned short* __restrict__ obf, float* __restrict__ ofp, int mode) {
  __shared__ unsigned short As[8][64][8];    // [k/8][m][8k]
  __shared__ unsigned short Bs[8][128][8];   // [k/8][n][8k]
  const int t = threadIdx.x;
  const int m0 = blockIdx.x * 64, n0 = blockIdx.y * 128;
  const int w = t >> 6, lane = t & 63, g = lane >> 4, ln = lane & 15;
  const int wm = w >> 1, wn = w & 1;

  f32x4 acc[2][4];
  #pragma unroll
  for (int i = 0; i < 2; i++)
    #pragma unroll
    for (int j = 0; j < 4; j++) acc[i][j] = (f32x4){0.f, 0.f, 0.f, 0.f};

  const int arow = t >> 2, apart = t & 3;
  const int brow = t >> 1, bhalf = t & 1;

  for (int k0 = 0; k0 < 512; k0 += 64) {
    __syncthreads();
    {
      const uint4* ga = (const uint4*)(A + (size_t)(m0 + arow) * 512 + k0 + apart * 16);
      uint4 u0 = ga[0], u1 = ga[1];
      *(uint4*)&As[apart * 2][arow][0]     = u0;
      *(uint4*)&As[apart * 2 + 1][arow][0] = u1;
      const uint4* gb = (const uint4*)(Bt + (size_t)(n0 + brow) * 512 + k0 + bhalf * 32);
      uint4 v0 = gb[0], v1 = gb[1], v2 = gb[2], v3 = gb[3];
      *(uint4*)&Bs[bhalf * 4][brow][0]     = v0;
      *(uint4*)&Bs[bhalf * 4 + 1][brow][0] = v1;
      *(uint4*)&Bs[bhalf * 4 + 2][brow][0] = v2;
      *(uint4*)&Bs[bhalf * 4 + 3][brow][0] = v3;
    }
    __syncthreads();
    #pragma unroll
    for (int ks = 0; ks < 2; ks++) {
      bf16x8 af[2], bfr[4];
      #pragma unroll
      for (int i = 0; i < 2; i++)
        af[i] = *(const bf16x8*)&As[ks * 4 + g][wm * 32 + i * 16 + ln][0];
      #pragma unroll
      for (int j = 0; j < 4; j++)
        bfr[j] = *(const bf16x8*)&Bs[ks * 4 + g][wn * 64 + j * 16 + ln][0];
      #pragma unroll
      for (int i = 0; i < 2; i++)
        #pragma unroll
        for (int j = 0; j < 4; j++)
          acc[i][j] = MFMA(af[i], bfr[j], acc[i][j], 0, 0, 0);
    }
  }

  #pragma unroll
  for (int j = 0; j < 4; j++) {
    const int n = n0 + wn * 64 + j * 16 + ln;
    const float bn = bias[n];
    const float wgn = (mode == 1) ? wg512[n] : 0.f;
    #pragma unroll
    for (int i = 0; i < 2; i++) {
      #pragma unroll
      for (int r = 0; r < 4; r++) {
        const int m = m0 + wm * 32 + i * 16 + g * 4 + r;
        const float v = acc[i][j][r] + bn;
        if (mode == 0) {
          obf[(size_t)m * 512 + n] = f2b(v);
        } else if (mode == 1) {
          const float gate = sigm(v + trust[m] * wgn);
          obf[(size_t)m * 512 + n] = f2b(Afp[(size_t)m * 512 + n] * gate);
        } else {
          ofp[(size_t)m * 512 + n] = v;
        }
      }
    }
  }
}

// ---------------------------------------------------------------------------
// Fused attention: per (bh, 32 q-rows). 512 threads (8 waves).
//  QK^T (MFMA, direct global frags) -> exp (no max-sub; scores bounded) ->
//  p bf16 in LDS + row sums -> write attn = p/L once -> PV (MFMA, attended^T)
// ---------------------------------------------------------------------------
__global__ __launch_bounds__(512) void k_attn(
    const unsigned short* __restrict__ Qb, const unsigned short* __restrict__ Kb,
    const unsigned short* __restrict__ Vt, const float* __restrict__ trust,
    const float* __restrict__ ts, float* __restrict__ attn,
    float* __restrict__ attf, unsigned short* __restrict__ attb) {
  __shared__ unsigned short pb[32][2056];   // unnormalized exp(s), bf16
  __shared__ float tks[2048];
  __shared__ float attS[32][68];
  __shared__ float Lsum[32];
  __shared__ float invLs[32];

  const int t = threadIdx.x;
  const int q0 = blockIdx.x * 32;
  const int bh = blockIdx.y, b = bh >> 3, h = bh & 7;
  const int w = t >> 6, lane = t & 63, g = lane >> 4, ln = lane & 15;

  *(float4*)(tks + t * 4) = *(const float4*)(trust + b * SEQ + t * 4);
  if (t < 32) Lsum[t] = 0.f;
  const float sa = ts[0], sb = ts[1], sc = ts[2];
  __syncthreads();

  // ---- QK^T: wave = (qh, kr): q-half 16 rows, 512-key range ----
  const int qh = w & 1, kr = w >> 1;
  const unsigned short* qptr = Qb + (size_t)(b * SEQ + q0 + qh * 16 + ln) * 512 + h * 64;
  const bf16x8 qf0 = *(const bf16x8*)(qptr + g * 8);
  const bf16x8 qf1 = *(const bf16x8*)(qptr + 32 + g * 8);
  float tq[4];
  #pragma unroll
  for (int r = 0; r < 4; r++) tq[r] = tks[q0 + qh * 16 + g * 4 + r];
  float rs[4] = {0.f, 0.f, 0.f, 0.f};

  #pragma unroll 2
  for (int kt = 0; kt < 32; kt++) {
    const int k0 = kr * 512 + kt * 16;
    const unsigned short* kptr = Kb + (size_t)(b * SEQ + k0 + ln) * 512 + h * 64;
    const bf16x8 kf0 = *(const bf16x8*)(kptr + g * 8);
    const bf16x8 kf1 = *(const bf16x8*)(kptr + 32 + g * 8);
    f32x4 acc = (f32x4){0.f, 0.f, 0.f, 0.f};
    acc = MFMA(qf0, kf0, acc, 0, 0, 0);
    acc = MFMA(qf1, kf1, acc, 0, 0, 0);
    const float tkn = tks[k0 + ln];
    #pragma unroll
    for (int r = 0; r < 4; r++) {
      const float aff = sigm(sa * tq[r] * tkn + sb * (tq[r] + tkn) + sc);
      const float s = acc[r] * 0.125f + 0.1f * aff;
      const float p = __expf(s);
      rs[r] += p;
      pb[qh * 16 + g * 4 + r][k0 + ln] = f2b(p);
    }
  }
  #pragma unroll
  for (int r = 0; r < 4; r++) {
    float v = rs[r];
    v += __shfl_xor(v, 1); v += __shfl_xor(v, 2);
    v += __shfl_xor(v, 4); v += __shfl_xor(v, 8);
    if (ln == 0) atomicAdd(&Lsum[qh * 16 + g * 4 + r], v);
  }
  __syncthreads();
  if (t < 32) invLs[t] = 1.f / Lsum[t];
  __syncthreads();

  // ---- write attn = p * invL (537MB total: the HBM floor) ----
  {
    const int row = t >> 4, c0 = (t & 15) * 4;
    const float il = invLs[row];
    float* dst = attn + ((size_t)bh * SEQ + q0 + row) * SEQ;
    #pragma unroll 4
    for (int it = 0; it < 32; it++) {
      const int c = it * 64 + c0;
      const uint2 v = *(const uint2*)&pb[row][c];
      float4 o;
      o.x = b2f(v.x & 0xffffu) * il; o.y = b2f(v.x >> 16) * il;
      o.z = b2f(v.y & 0xffffu) * il; o.w = b2f(v.y >> 16) * il;
      *(float4*)(dst + c) = o;
    }
  }

  // ---- PV: attended^T[d][q] = sum_k V^T[d][k] * P^T[k][q]; wave = (qh2, dt) ----
  {
    const int dt = w & 3, qh2 = w >> 2;
    f32x4 a0 = (f32x4){0.f, 0.f, 0.f, 0.f}, a1 = a0;
    const unsigned short* vrow = Vt + (size_t)(bh * 64 + dt * 16 + ln) * SEQ;
    const unsigned short* prow = &pb[qh2 * 16 + ln][0];
    #pragma unroll 4
    for (int kt = 0; kt < 32; kt++) {
      const bf16x8 v0 = *(const bf16x8*)(vrow + kt * 32 + g * 8);
      const bf16x8 p0 = *(const bf16x8*)(prow + kt * 32 + g * 8);
      a0 = MFMA(v0, p0, a0, 0, 0, 0);
      const bf16x8 v1 = *(const bf16x8*)(vrow + 1024 + kt * 32 + g * 8);
      const bf16x8 p1 = *(const bf16x8*)(prow + 1024 + kt * 32 + g * 8);
      a1 = MFMA(v1, p1, a1, 0, 0, 0);
    }
    const float il = invLs[qh2 * 16 + ln];
    #pragma unroll
    for (int r = 0; r < 4; r++)
      attS[qh2 * 16 + ln][dt * 16 + g * 4 + r] = (a0[r] + a1[r]) * il;
  }
  __syncthreads();
  {
    const int row = t >> 4, d0 = (t & 15) * 4;
    const size_t gbase = (size_t)(b * SEQ + q0 + row) * 512 + h * 64 + d0;
    const float4 v = *(const float4*)&attS[row][d0];
    *(float4*)(attf + gbase) = v;
    uint2 o;
    o.x = (unsigned)f2b(v.x) | ((unsigned)f2b(v.y) << 16);
    o.y = (unsigned)f2b(v.z) | ((unsigned)f2b(v.w) << 16);
    *(uint2*)(attb + gbase) = o;
  }
}

// ---------------------------------------------------------------------------
extern "C" void kernel_launch(void* const* d_in, const int* in_sizes, int n_in,
                              void* d_out, int out_size, void* d_ws, size_t ws_size,
                              hipStream_t stream) {
  const float* x     = (const float*)d_in[0];
  const float* trust = (const float*)d_in[1];
  const float* Wq = (const float*)d_in[2];  const float* bq = (const float*)d_in[3];
  const float* Wk = (const float*)d_in[4];  const float* bk = (const float*)d_in[5];
  const float* Wv = (const float*)d_in[6];  const float* bv = (const float*)d_in[7];
  const float* Wt = (const float*)d_in[8];  const float* bt = (const float*)d_in[9];
  const float* Wg = (const float*)d_in[10]; const float* bg = (const float*)d_in[11];
  const float* Wo = (const float*)d_in[12]; const float* bo = (const float*)d_in[13];

  float* out  = (float*)d_out;
  float* attn = out + OUT_ATTN;
  char* ws = (char*)d_ws;

  unsigned short* xb   = (unsigned short*)(ws + OFF_XB);
  unsigned short* Qb   = (unsigned short*)(ws + OFF_QB);
  unsigned short* Kb   = (unsigned short*)(ws + OFF_KB);
  unsigned short* Vb   = (unsigned short*)(ws + OFF_VB);
  unsigned short* Vtb  = (unsigned short*)(ws + OFF_XB);    // overwrites x (dead)
  unsigned short* attb = (unsigned short*)(ws + OFF_VB);    // overwrites V (dead)
  unsigned short* gatb = (unsigned short*)(ws + OFF_KB);    // overwrites K (dead)
  float* attf = (float*)(ws + OFF_ATTF);
  unsigned short* Wqt = (unsigned short*)(ws + OFF_WQT);
  unsigned short* Wkt = (unsigned short*)(ws + OFF_WKT);
  unsigned short* Wvt = (unsigned short*)(ws + OFF_WVT);
  unsigned short* Wgt = (unsigned short*)(ws + OFF_WGT);
  unsigned short* Wot = (unsigned short*)(ws + OFF_WOT);
  float* tsp = (float*)(ws + OFF_TS);

  k_trust_scalars<<<1, 64, 0, stream>>>(Wt, bt, tsp);
  k_cvt_x<<<2048, 256, 0, stream>>>(x, xb);
  dim3 wg(8, 8);
  k_wtrans<<<wg, 256, 0, stream>>>(Wq, Wqt);
  k_wtrans<<<wg, 256, 0, stream>>>(Wk, Wkt);
  k_wtrans<<<wg, 256, 0, stream>>>(Wv, Wvt);
  k_wtrans<<<wg, 256, 0, stream>>>(Wg, Wgt);   // first 512 rows of Wg
  k_wtrans<<<wg, 256, 0, stream>>>(Wo, Wot);

  dim3 gg(128, 4);
  k_gemm<<<gg, 256, 0, stream>>>(xb, Wqt, bq, nullptr, nullptr, nullptr, Qb, nullptr, 0);
  k_gemm<<<gg, 256, 0, stream>>>(xb, Wkt, bk, nullptr, nullptr, nullptr, Kb, nullptr, 0);
  k_gemm<<<gg, 256, 0, stream>>>(xb, Wvt, bv, nullptr, nullptr, nullptr, Vb, nullptr, 0);

  k_vtrans<<<dim3(32, 32), 256, 0, stream>>>(Vb, Vtb);

  k_attn<<<dim3(64, 32), 512, 0, stream>>>(Qb, Kb, Vtb, trust, tsp, attn, attf, attb);

  k_gemm<<<gg, 256, 0, stream>>>(attb, Wgt, bg, Wg + 512 * 512, trust, attf,
                                 gatb, nullptr, 1);
  k_gemm<<<gg, 256, 0, stream>>>(gatb, Wot, bo, nullptr, nullptr, nullptr,
                                 nullptr, out, 2);
}